// Round 1
// baseline (16510.619 us; speedup 1.0000x reference)
//
#include <hip/hip_runtime.h>
#include <math.h>

#define HID 256
#define TWOH 512
#define BS_ROWS 8192   // B*S = 8*1024
#define NLAYER 4
#define TMAX 50
#define DT 0.05f
#define EPSC 1e-3f

// GEMM tiling
#define BM 64
#define BN 128
#define BK 16

// ---------------------------------------------------------------------------
// Weight packing: Wp[k][n], k in [0,512) over combined=[cur_in|h_prev],
// n = 2d   -> tau column d    : Wt[d][k]
// n = 2d+1 -> forcing column d: k<256 ? Wi[d][k] : Ws[d][k-256]
// ---------------------------------------------------------------------------
__global__ void pack_w_kernel(const float* __restrict__ Ws,
                              const float* __restrict__ Wi,
                              const float* __restrict__ Wt,
                              float* __restrict__ Wp) {
    int idx = blockIdx.x * 256 + threadIdx.x;           // [0, 4*512*512)
    int L   = idx / (TWOH * TWOH);
    int rem = idx % (TWOH * TWOH);
    int k   = rem / TWOH;
    int n   = rem % TWOH;
    int d   = n >> 1;
    float v;
    if ((n & 1) == 0) {
        v = Wt[(size_t)L * HID * TWOH + (size_t)d * TWOH + k];
    } else {
        v = (k < HID) ? Wi[(size_t)L * HID * HID + (size_t)d * HID + k]
                      : Ws[(size_t)L * HID * HID + (size_t)d * HID + (k - HID)];
    }
    Wp[idx] = v;
}

__global__ void pack_b_kernel(const float* __restrict__ bs,
                              const float* __restrict__ bi,
                              const float* __restrict__ bt,
                              float* __restrict__ bp) {
    int idx = blockIdx.x * 256 + threadIdx.x;           // [0, 4*512)
    int L = idx / TWOH;
    int n = idx % TWOH;
    int d = n >> 1;
    bp[idx] = ((n & 1) == 0) ? bt[L * HID + d]
                             : (bs[L * HID + d] + bi[L * HID + d]);
}

__global__ void init_kernel(float* __restrict__ deltas, int* __restrict__ done,
                            float* __restrict__ result) {
    int i = threadIdx.x;
    if (i < TMAX) deltas[i] = 0.0f;
    if (i == 0) { *done = 0; *result = (float)TMAX; }
}

// ---------------------------------------------------------------------------
// Fused layer kernel: C[8192,512] = [cur_in|h_prev] @ Wp, then activation
// epilogue producing h_new in place of the layer's state slab (ping-pong).
// ---------------------------------------------------------------------------
__global__ __launch_bounds__(256) void layer_kernel(
    const float* __restrict__ curin,   // [8192][256]
    const float* __restrict__ hprev,   // [8192][256]  (old states of layer)
    float* __restrict__ hnew,          // [8192][256]  (new states of layer)
    const float* __restrict__ Wp,      // [512][512] k-major, interleaved cols
    const float* __restrict__ bp,      // [512] interleaved biases
    const int* __restrict__ done,
    float* __restrict__ delta_slot)
{
    const int tid = threadIdx.x;
    const int m0 = blockIdx.x * BM;
    const int n0 = blockIdx.y * BN;

    if (*done) {
        // Frozen: states pass through unchanged (jnp.where(done, states, new)).
        const int d0 = n0 >> 1;                     // 64-wide d-range
        const int dcol = d0 + (tid & 15) * 4;
        #pragma unroll
        for (int p = 0; p < 4; ++p) {
            int row = m0 + (tid >> 4) + p * 16;
            *(float4*)(hnew + (size_t)row * HID + dcol) =
                *(const float4*)(hprev + (size_t)row * HID + dcol);
        }
        return;
    }

    __shared__ float As[BK][BM + 4];   // 16 x 68 (b128-aligned rows)
    __shared__ float Bs[BK][BN + 4];   // 16 x 132

    float acc[4][8];
    #pragma unroll
    for (int i = 0; i < 4; ++i)
        #pragma unroll
        for (int j = 0; j < 8; ++j) acc[i][j] = 0.0f;

    const int ty = tid >> 4;           // 0..15 -> M
    const int tx = tid & 15;           // 0..15 -> N

    const int arow = tid >> 2;         // 0..63
    const int aseg = tid & 3;          // 0..3
    const int brow = tid >> 4;         // 0..15
    const int bcol = (tid & 15) << 3;  // 0..120

    for (int k0 = 0; k0 < TWOH; k0 += BK) {
        const float* asrc = (k0 < HID)
            ? (curin + (size_t)(m0 + arow) * HID + (k0 + aseg * 4))
            : (hprev + (size_t)(m0 + arow) * HID + (k0 - HID + aseg * 4));
        const float4 av  = *(const float4*)asrc;
        const float4 bv0 = *(const float4*)(Wp + (size_t)(k0 + brow) * TWOH + n0 + bcol);
        const float4 bv1 = *(const float4*)(Wp + (size_t)(k0 + brow) * TWOH + n0 + bcol + 4);

        __syncthreads();
        As[aseg * 4 + 0][arow] = av.x;
        As[aseg * 4 + 1][arow] = av.y;
        As[aseg * 4 + 2][arow] = av.z;
        As[aseg * 4 + 3][arow] = av.w;
        *(float4*)&Bs[brow][bcol]     = bv0;
        *(float4*)&Bs[brow][bcol + 4] = bv1;
        __syncthreads();

        #pragma unroll
        for (int kk = 0; kk < BK; ++kk) {
            const float4 a  = *(const float4*)&As[kk][ty * 4];
            const float4 b0 = *(const float4*)&Bs[kk][tx * 8];
            const float4 b1 = *(const float4*)&Bs[kk][tx * 8 + 4];
            const float av4[4] = {a.x, a.y, a.z, a.w};
            const float bv8[8] = {b0.x, b0.y, b0.z, b0.w, b1.x, b1.y, b1.z, b1.w};
            #pragma unroll
            for (int i = 0; i < 4; ++i)
                #pragma unroll
                for (int j = 0; j < 8; ++j)
                    acc[i][j] += av4[i] * bv8[j];
        }
    }

    // Epilogue: this thread owns rows m0+ty*4..+3, n-cols nb..nb+7 => d dbase..+3
    const int nb = n0 + tx * 8;
    const int dbase = nb >> 1;
    const float4 bpa = *(const float4*)(bp + nb);
    const float4 bpb = *(const float4*)(bp + nb + 4);
    const float bt4[4] = {bpa.x, bpa.z, bpb.x, bpb.z};   // tau biases
    const float bf4[4] = {bpa.y, bpa.w, bpb.y, bpb.w};   // forcing biases

    float dmax = 0.0f;
    #pragma unroll
    for (int i = 0; i < 4; ++i) {
        const int row = m0 + ty * 4 + i;
        const float* hp = hprev + (size_t)row * HID;
        float* hn = hnew + (size_t)row * HID;
        #pragma unroll
        for (int jj = 0; jj < 4; ++jj) {
            float tpre = acc[i][2 * jj]     + bt4[jj];
            float fpre = acc[i][2 * jj + 1] + bf4[jj];
            float tau  = 1.0f / (1.0f + expf(-tpre)) + 1e-6f;
            float fo   = tanhf(fpre);
            float h    = hp[dbase + jj];
            float v    = h + DT * (fo - h / tau);
            v = fminf(10.0f, fmaxf(-10.0f, v));
            hn[dbase + jj] = v;
            dmax = fmaxf(dmax, fabsf(v - h));
        }
    }

    // Wave reduction (64 lanes), then one atomic per wave.
    #pragma unroll
    for (int off = 32; off > 0; off >>= 1)
        dmax = fmaxf(dmax, __shfl_xor(dmax, off, 64));
    if ((tid & 63) == 0)
        atomicMax((unsigned int*)delta_slot, __float_as_uint(dmax));
}

__global__ void conv_kernel(const float* __restrict__ delta_slot,
                            int* __restrict__ done, float* __restrict__ result,
                            int t) {
    if (*done) return;
    float dm = __uint_as_float(*(const unsigned int*)delta_slot);
    if (dm < EPSC) { *result = (float)t; *done = 1; }
}

__global__ void final_kernel(const float* __restrict__ src,
                             const float* __restrict__ result,
                             float* __restrict__ out) {
    int idx = blockIdx.x * blockDim.x + threadIdx.x;    // 524288 float4s
    ((float4*)out)[idx] = ((const float4*)src)[idx];
    if (idx == 0) out[(size_t)BS_ROWS * HID] = *result;
}

// ---------------------------------------------------------------------------
extern "C" void kernel_launch(void* const* d_in, const int* in_sizes, int n_in,
                              void* d_out, int out_size, void* d_ws, size_t ws_size,
                              hipStream_t stream) {
    const float* x  = (const float*)d_in[0];
    const float* Ws = (const float*)d_in[1];
    const float* bs = (const float*)d_in[2];
    const float* Wi = (const float*)d_in[3];
    const float* bi = (const float*)d_in[4];
    const float* Wt = (const float*)d_in[5];
    const float* bt = (const float*)d_in[6];
    float* out = (float*)d_out;

    const size_t slab = (size_t)NLAYER * BS_ROWS * HID;   // floats per state set
    char* p = (char*)d_ws;
    float* statesA = (float*)p; p += slab * sizeof(float);                 // 32 MB
    float* statesB = (float*)p; p += slab * sizeof(float);                 // 32 MB
    float* Wp      = (float*)p; p += (size_t)NLAYER * TWOH * TWOH * 4;     //  4 MB
    float* bp      = (float*)p; p += (size_t)NLAYER * TWOH * 4;
    float* deltas  = (float*)p; p += 256;
    int*   done    = (int*)p;   p += 256;
    float* result  = (float*)p; p += 256;

    hipMemsetAsync(statesA, 0, slab * sizeof(float), stream);
    init_kernel<<<1, 64, 0, stream>>>(deltas, done, result);
    pack_w_kernel<<<(NLAYER * TWOH * TWOH) / 256, 256, 0, stream>>>(Ws, Wi, Wt, Wp);
    pack_b_kernel<<<(NLAYER * TWOH) / 256, 256, 0, stream>>>(bs, bi, bt, bp);

    for (int t = 0; t < TMAX; ++t) {
        float* oldS = (t & 1) ? statesB : statesA;
        float* newS = (t & 1) ? statesA : statesB;
        for (int L = 0; L < NLAYER; ++L) {
            const float* curin = (L == 0) ? x : (newS + (size_t)(L - 1) * BS_ROWS * HID);
            layer_kernel<<<dim3(BS_ROWS / BM, TWOH / BN), 256, 0, stream>>>(
                curin,
                oldS + (size_t)L * BS_ROWS * HID,
                newS + (size_t)L * BS_ROWS * HID,
                Wp + (size_t)L * TWOH * TWOH,
                bp + (size_t)L * TWOH,
                done, deltas + t);
        }
        conv_kernel<<<1, 1, 0, stream>>>(deltas + t, done, result, t);
    }
    // After t=49 (odd), newS == statesA holds the final states.
    final_kernel<<<(BS_ROWS * HID / 4) / 256, 256, 0, stream>>>(
        statesA + (size_t)3 * BS_ROWS * HID, result, out);
}

// Round 2
// 7506.971 us; speedup vs baseline: 2.1994x; 2.1994x over previous
//
#include <hip/hip_runtime.h>
#include <math.h>

#define HID 256
#define TWOH 512
#define ROWS 8192   // B*S = 8*1024
#define NLAYER 4
#define TMAX 50
#define DT 0.05f
#define EPSC 1e-3f

// GEMM tiling: C[8192,512] = A[8192,512] * B[512,512]
#define BM 64
#define BN 128
#define BK 64

typedef __bf16 bf16;
typedef __bf16 bf16x8 __attribute__((ext_vector_type(8)));
typedef __bf16 bf16x4 __attribute__((ext_vector_type(4)));
typedef float f32x4 __attribute__((ext_vector_type(4)));

typedef const __attribute__((address_space(1))) unsigned int* gp_t;
typedef __attribute__((address_space(3))) unsigned int* lp_t;

// ---------------------------------------------------------------------------
// Weight packing: WpT[n][k] (n-major, bf16), n-cols interleaved:
//   n=2d   -> tau column d    : Wt[d][k]
//   n=2d+1 -> forcing column d: k<256 ? Wi[d][k] : Ws[d][k-256]
// ---------------------------------------------------------------------------
__global__ void pack_w_kernel(const float* __restrict__ Ws,
                              const float* __restrict__ Wi,
                              const float* __restrict__ Wt,
                              bf16* __restrict__ WpT) {
    int idx = blockIdx.x * 256 + threadIdx.x;           // [0, 4*512*512)
    int L   = idx / (TWOH * TWOH);
    int rem = idx % (TWOH * TWOH);
    int n   = rem / TWOH;
    int k   = rem % TWOH;
    int d   = n >> 1;
    float v;
    if ((n & 1) == 0) {
        v = Wt[(size_t)L * HID * TWOH + (size_t)d * TWOH + k];
    } else {
        v = (k < HID) ? Wi[(size_t)L * HID * HID + (size_t)d * HID + k]
                      : Ws[(size_t)L * HID * HID + (size_t)d * HID + (k - HID)];
    }
    WpT[idx] = (bf16)v;
}

__global__ void pack_b_kernel(const float* __restrict__ bs,
                              const float* __restrict__ bi,
                              const float* __restrict__ bt,
                              float* __restrict__ bp) {
    int idx = blockIdx.x * 256 + threadIdx.x;           // [0, 4*512)
    int L = idx / TWOH;
    int n = idx % TWOH;
    int d = n >> 1;
    bp[idx] = ((n & 1) == 0) ? bt[L * HID + d]
                             : (bs[L * HID + d] + bi[L * HID + d]);
}

__global__ void cvt_kernel(const float* __restrict__ src, bf16* __restrict__ dst) {
    int i = blockIdx.x * 256 + threadIdx.x;             // float4 index
    float4 v = ((const float4*)src)[i];
    bf16x4 o = {(bf16)v.x, (bf16)v.y, (bf16)v.z, (bf16)v.w};
    ((bf16x4*)dst)[i] = o;
}

__global__ void init_kernel(float* __restrict__ deltas, int* __restrict__ done,
                            float* __restrict__ result) {
    int i = threadIdx.x;
    if (i < 64) deltas[i] = 0.0f;
    if (i == 0) { *done = 0; *result = (float)TMAX; }
}

// ---------------------------------------------------------------------------
// Fused bf16-MFMA layer kernel.
//   A = [curin16 | hprev16]  (k<256 left, k>=256 right), bf16 [8192][256] each
//   B = WpT (read as B[k][n] via n-major storage)
// Epilogue: tau/forcing pairing via shfl_xor(1); h updated in fp32 IN PLACE
// (each (row,d) read+written by the same thread); bf16 copy to hnew16 for the
// next layer/iteration's matmul input.
// ---------------------------------------------------------------------------
__global__ __launch_bounds__(256) void layer_kernel(
    const bf16* __restrict__ curin16,
    const bf16* __restrict__ hprev16,
    bf16* __restrict__ hnew16,
    float* __restrict__ h32,
    const bf16* __restrict__ WpT,
    const float* __restrict__ bp,
    const int* __restrict__ done,
    float* __restrict__ delta_slot)
{
    __shared__ bf16 As[BM * BK];    // 64 rows x 64 k (8 KB), XOR-swizzled segs
    __shared__ bf16 Bs[BN * BK];    // 128 rows x 64 k (16 KB)

    if (*done) return;              // frozen: h32 untouched, nothing to do

    const int tid  = threadIdx.x;
    const int m0   = blockIdx.x * BM;
    const int n0   = blockIdx.y * BN;
    const int lane = tid & 63;
    const int wv   = tid >> 6;      // wave 0..3
    const int l15  = lane & 15;
    const int quad = lane >> 4;     // 0..3
    const int mb   = (wv & 1) * 32; // wave's m-offset in tile
    const int nb   = (wv >> 1) * 64;// wave's n-offset in tile

    f32x4 acc[2][4];
    #pragma unroll
    for (int mt = 0; mt < 2; ++mt)
        #pragma unroll
        for (int nt = 0; nt < 4; ++nt)
            acc[mt][nt] = (f32x4){0.f, 0.f, 0.f, 0.f};

    // staging map: thread -> (row = c*32 + tid>>3, seg = tid&7), 16 B per lane.
    const int srow = tid >> 3;          // 0..31
    const int sseg = tid & 7;
    const int swz  = sseg ^ (srow & 7); // XOR swizzle (row&7 == srow&7 since c*32 % 8 == 0)

    for (int k0 = 0; k0 < TWOH; k0 += BK) {
        const bf16* abase = curin16;
        int kk = k0;
        if (k0 >= HID) { abase = hprev16; kk = k0 - HID; }

        __syncthreads();   // previous iter's ds_reads must finish before overwrite
        #pragma unroll
        for (int c = 0; c < 2; ++c) {
            const bf16* g = abase + (size_t)(m0 + c * 32 + srow) * HID + kk + swz * 8;
            __builtin_amdgcn_global_load_lds((gp_t)g, (lp_t)&As[c * 2048 + wv * 512], 16, 0, 0);
        }
        #pragma unroll
        for (int c = 0; c < 4; ++c) {
            const bf16* g = WpT + (size_t)(n0 + c * 32 + srow) * TWOH + k0 + swz * 8;
            __builtin_amdgcn_global_load_lds((gp_t)g, (lp_t)&Bs[c * 2048 + wv * 512], 16, 0, 0);
        }
        __syncthreads();   // compiler drains vmcnt before barrier -> LDS ready

        #pragma unroll
        for (int kw = 0; kw < 2; ++kw) {
            const int seg = kw * 4 + quad;
            bf16x8 af[2], bfr[4];
            #pragma unroll
            for (int mt = 0; mt < 2; ++mt) {
                int r = mb + mt * 16 + l15;
                af[mt] = *(const bf16x8*)&As[r * 64 + ((seg ^ (r & 7)) * 8)];
            }
            #pragma unroll
            for (int nt = 0; nt < 4; ++nt) {
                int r = nb + nt * 16 + l15;
                bfr[nt] = *(const bf16x8*)&Bs[r * 64 + ((seg ^ (r & 7)) * 8)];
            }
            #pragma unroll
            for (int mt = 0; mt < 2; ++mt)
                #pragma unroll
                for (int nt = 0; nt < 4; ++nt)
                    acc[mt][nt] = __builtin_amdgcn_mfma_f32_16x16x32_bf16(
                        af[mt], bfr[nt], acc[mt][nt], 0, 0, 0);
        }
    }

    // Epilogue. C/D layout: col = lane&15, row = quad*4 + reg.
    // col even -> tau-pre for d=col/2 ; col odd -> forcing-pre (partner lane^1).
    float dmax = 0.0f;
    #pragma unroll
    for (int mt = 0; mt < 2; ++mt) {
        #pragma unroll
        for (int nt = 0; nt < 4; ++nt) {
            f32x4 v = acc[mt][nt];
            float pf[4];
            #pragma unroll
            for (int r = 0; r < 4; ++r) pf[r] = __shfl_xor(v[r], 1);
            if ((lane & 1) == 0) {
                const int col  = n0 + nb + nt * 16 + l15;   // even
                const int d    = col >> 1;
                const float btau = bp[col];
                const float bfor = bp[col + 1];
                const int rowb = m0 + mb + mt * 16 + quad * 4;
                #pragma unroll
                for (int r = 0; r < 4; ++r) {
                    float tpre = v[r] + btau;
                    float fpre = pf[r] + bfor;
                    tpre = fminf(30.f, fmaxf(-30.f, tpre));
                    fpre = fminf(15.f, fmaxf(-15.f, fpre));
                    float tau = 1.0f / (1.0f + __expf(-tpre)) + 1e-6f;
                    float e2  = __expf(2.0f * fpre);
                    float fo  = (e2 - 1.0f) / (e2 + 1.0f);
                    size_t idx = (size_t)(rowb + r) * HID + d;
                    float h  = h32[idx];
                    float nv = h + DT * (fo - h / tau);
                    nv = fminf(10.0f, fmaxf(-10.0f, nv));
                    h32[idx] = nv;
                    hnew16[idx] = (bf16)nv;
                    dmax = fmaxf(dmax, fabsf(nv - h));
                }
            }
        }
    }
    #pragma unroll
    for (int off = 32; off > 0; off >>= 1)
        dmax = fmaxf(dmax, __shfl_xor(dmax, off));
    if (lane == 0)
        atomicMax((unsigned int*)delta_slot, __float_as_uint(dmax));
}

__global__ void conv_kernel(const float* __restrict__ delta_slot,
                            int* __restrict__ done, float* __restrict__ result,
                            int t) {
    if (*done) return;
    float dm = __uint_as_float(*(const unsigned int*)delta_slot);
    if (dm < EPSC) { *result = (float)t; *done = 1; }
}

__global__ void final_kernel(const float* __restrict__ src,
                             const float* __restrict__ result,
                             float* __restrict__ out) {
    int idx = blockIdx.x * blockDim.x + threadIdx.x;    // 524288 float4s
    ((float4*)out)[idx] = ((const float4*)src)[idx];
    if (idx == 0) out[(size_t)ROWS * HID] = *result;
}

// ---------------------------------------------------------------------------
extern "C" void kernel_launch(void* const* d_in, const int* in_sizes, int n_in,
                              void* d_out, int out_size, void* d_ws, size_t ws_size,
                              hipStream_t stream) {
    const float* x  = (const float*)d_in[0];
    const float* Ws = (const float*)d_in[1];
    const float* bs = (const float*)d_in[2];
    const float* Wi = (const float*)d_in[3];
    const float* bi = (const float*)d_in[4];
    const float* Wt = (const float*)d_in[5];
    const float* bt = (const float*)d_in[6];
    float* out = (float*)d_out;

    const size_t slab   = (size_t)ROWS * HID;            // elems per layer-state
    char* p = (char*)d_ws;
    float* h32    = (float*)p; p += NLAYER * slab * sizeof(float);   // 32 MB, in-place fp32 states
    bf16*  s16A   = (bf16*)p;  p += NLAYER * slab * sizeof(bf16);    // 16 MB bf16 ping
    bf16*  s16B   = (bf16*)p;  p += NLAYER * slab * sizeof(bf16);    // 16 MB bf16 pong
    bf16*  xb     = (bf16*)p;  p += slab * sizeof(bf16);             //  4 MB
    bf16*  WpT    = (bf16*)p;  p += (size_t)NLAYER * TWOH * TWOH * sizeof(bf16); // 2 MB
    float* bp     = (float*)p; p += (size_t)NLAYER * TWOH * sizeof(float);
    float* deltas = (float*)p; p += 64 * sizeof(float);
    int*   done   = (int*)p;   p += 256;
    float* result = (float*)p; p += 256;

    hipMemsetAsync(h32, 0, NLAYER * slab * sizeof(float), stream);
    hipMemsetAsync(s16A, 0, NLAYER * slab * sizeof(bf16), stream);
    init_kernel<<<1, 64, 0, stream>>>(deltas, done, result);
    pack_w_kernel<<<(NLAYER * TWOH * TWOH) / 256, 256, 0, stream>>>(Ws, Wi, Wt, WpT);
    pack_b_kernel<<<(NLAYER * TWOH) / 256, 256, 0, stream>>>(bs, bi, bt, bp);
    cvt_kernel<<<(ROWS * HID / 4) / 256, 256, 0, stream>>>(x, xb);

    for (int t = 0; t < TMAX; ++t) {
        bf16* oldS = (t & 1) ? s16B : s16A;
        bf16* newS = (t & 1) ? s16A : s16B;
        for (int L = 0; L < NLAYER; ++L) {
            const bf16* curin = (L == 0) ? xb : (newS + (size_t)(L - 1) * slab);
            layer_kernel<<<dim3(ROWS / BM, TWOH / BN), 256, 0, stream>>>(
                curin,
                oldS + (size_t)L * slab,
                newS + (size_t)L * slab,
                h32  + (size_t)L * slab,
                WpT  + (size_t)L * TWOH * TWOH,
                bp   + (size_t)L * TWOH,
                done, deltas + t);
        }
        conv_kernel<<<1, 1, 0, stream>>>(deltas + t, done, result, t);
    }
    final_kernel<<<(ROWS * HID / 4) / 256, 256, 0, stream>>>(
        h32 + (size_t)3 * slab, result, out);
}

// Round 3
// 3634.555 us; speedup vs baseline: 4.5427x; 2.0654x over previous
//
#include <hip/hip_runtime.h>
#include <math.h>

#define HID 256
#define TWOH 512
#define ROWS 8192   // B*S
#define NLAYER 4
#define TMAX 50
#define DT 0.05f
#define EPSC 1e-3f

typedef __bf16 bf16;
typedef __bf16 bf16x8 __attribute__((ext_vector_type(8)));
typedef float f32x4 __attribute__((ext_vector_type(4)));

// ---------------------------------------------------------------------------
// Weight packing: WpT[n][k] (n-major, bf16), n-cols interleaved:
//   n=2d   -> tau column d    : Wt[d][k]
//   n=2d+1 -> forcing column d: k<256 ? Wi[d][k] : Ws[d][k-256]
// ---------------------------------------------------------------------------
__global__ void pack_w_kernel(const float* __restrict__ Ws,
                              const float* __restrict__ Wi,
                              const float* __restrict__ Wt,
                              bf16* __restrict__ WpT) {
    int idx = blockIdx.x * 256 + threadIdx.x;           // [0, 4*512*512)
    int L   = idx / (TWOH * TWOH);
    int rem = idx % (TWOH * TWOH);
    int n   = rem / TWOH;
    int k   = rem % TWOH;
    int d   = n >> 1;
    float v;
    if ((n & 1) == 0) {
        v = Wt[(size_t)L * HID * TWOH + (size_t)d * TWOH + k];
    } else {
        v = (k < HID) ? Wi[(size_t)L * HID * HID + (size_t)d * HID + k]
                      : Ws[(size_t)L * HID * HID + (size_t)d * HID + (k - HID)];
    }
    WpT[idx] = (bf16)v;
}

__global__ void pack_b_kernel(const float* __restrict__ bs,
                              const float* __restrict__ bi,
                              const float* __restrict__ bt,
                              float* __restrict__ bp) {
    int idx = blockIdx.x * 256 + threadIdx.x;           // [0, 4*512)
    int L = idx / TWOH;
    int n = idx % TWOH;
    int d = n >> 1;
    bp[idx] = ((n & 1) == 0) ? bt[L * HID + d]
                             : (bs[L * HID + d] + bi[L * HID + d]);
}

// ---------------------------------------------------------------------------
// Persistent kernel: block b owns rows [32b, 32b+32) for ALL 50 iters x 4
// layers. States are LDS-resident bf16 (XOR-swizzled segs of 8 for
// conflict-free ds_read_b128). Weights stream L2 -> registers (B-frags).
// 8 waves split n: wave w covers n-chunk [w*64, w*64+64).
// ---------------------------------------------------------------------------
__global__ __launch_bounds__(512, 1) void persistent_kernel(
    const float* __restrict__ x,
    const bf16* __restrict__ WpT,
    const float* __restrict__ bp,
    float* __restrict__ deltas,
    float* __restrict__ out)
{
    __shared__ bf16 sX[32 * 256];            // 16 KB
    __shared__ bf16 sH[NLAYER][32 * 256];    // 64 KB
    __shared__ bf16 sPad[8192];              // 16 KB pad -> 96 KB total (1 block/CU)

    const int tid  = threadIdx.x;
    const int lane = tid & 63;
    const int wv   = tid >> 6;               // 0..7
    const int l15  = lane & 15;
    const int quad = lane >> 4;              // 0..3
    const int w64  = wv * 64;
    const size_t rowbase = (size_t)blockIdx.x * 32;

    // ---- stage x -> sX (bf16, swizzled); zero sH; touch pad ----
    #pragma unroll
    for (int it = 0; it < 2; ++it) {
        int s = tid + it * 512;              // 0..1023 segs (32 rows x 32 segs)
        int r = s >> 5, seg = s & 31;
        const float* gx = x + (rowbase + r) * HID + seg * 8;
        float4 v0 = *(const float4*)gx;
        float4 v1 = *(const float4*)(gx + 4);
        bf16x8 o;
        o[0]=(bf16)v0.x; o[1]=(bf16)v0.y; o[2]=(bf16)v0.z; o[3]=(bf16)v0.w;
        o[4]=(bf16)v1.x; o[5]=(bf16)v1.y; o[6]=(bf16)v1.z; o[7]=(bf16)v1.w;
        int pseg = (seg & 24) | ((seg & 7) ^ (r & 7));
        *(bf16x8*)&sX[r * 256 + pseg * 8] = o;
    }
    {
        bf16x8 z = {};
        bf16* hflat = &sH[0][0];
        #pragma unroll
        for (int it = 0; it < 8; ++it)
            *(bf16x8*)&hflat[(size_t)(tid + it * 512) * 8] = z;
        *(bf16x8*)&sPad[tid * 8] = z;        // keep pad live
    }
    __syncthreads();

    for (int t = 0; t < TMAX; ++t) {
        float dmax = 0.0f;
        for (int L = 0; L < NLAYER; ++L) {
            const bf16* Alo = (L == 0) ? sX : sH[L - 1];   // k < 256  (cur_in)
            bf16*       Ahi = sH[L];                       // k >= 256 (h_prev)
            const bf16*  W  = WpT + (size_t)L * TWOH * TWOH;
            const float* bpL = bp + L * TWOH;
            const bf16*  wl = W + (size_t)(w64 + l15) * TWOH + quad * 8;

            f32x4 acc[2][4];
            #pragma unroll
            for (int mt = 0; mt < 2; ++mt)
                #pragma unroll
                for (int nt = 0; nt < 4; ++nt)
                    acc[mt][nt] = (f32x4){0.f, 0.f, 0.f, 0.f};

            bf16x8 bc[4], bn[4];
            #pragma unroll
            for (int nt = 0; nt < 4; ++nt)
                bc[nt] = *(const bf16x8*)(wl + (size_t)nt * 16 * TWOH);

            #pragma unroll
            for (int i = 0; i < 16; ++i) {                 // k = 32*i
                if (i < 15) {
                    #pragma unroll
                    for (int nt = 0; nt < 4; ++nt)
                        bn[nt] = *(const bf16x8*)(wl + (size_t)nt * 16 * TWOH + (i + 1) * 32);
                }
                const bf16* Asrc = (i < 8) ? Alo : Ahi;    // static under unroll
                const int segb = (i & 7) * 4 + quad;       // seg in [0,32)
                bf16x8 a[2];
                #pragma unroll
                for (int mt = 0; mt < 2; ++mt) {
                    int row  = mt * 16 + l15;
                    int pseg = (segb & 24) | ((segb & 7) ^ (row & 7));
                    a[mt] = *(const bf16x8*)&Asrc[row * 256 + pseg * 8];
                }
                #pragma unroll
                for (int mt = 0; mt < 2; ++mt)
                    #pragma unroll
                    for (int nt = 0; nt < 4; ++nt)
                        acc[mt][nt] = __builtin_amdgcn_mfma_f32_16x16x32_bf16(
                            a[mt], bc[nt], acc[mt][nt], 0, 0, 0);
                #pragma unroll
                for (int nt = 0; nt < 4; ++nt) bc[nt] = bn[nt];
            }

            __syncthreads();   // all MFMA reads of sH[L] done before overwrite

            // Epilogue. C/D: col = lane&15 (+16*nt +64*wv), row = quad*4+reg.
            // col even = tau-pre(d=col/2); odd = forcing-pre. Lane pair (l, l^1)
            // shares d; even lane handles regs 0,1, odd lane regs 2,3.
            {
                const int odd = lane & 1;
                #pragma unroll
                for (int nt = 0; nt < 4; ++nt) {
                    const int d = (w64 + nt * 16 + l15) >> 1;
                    const float2 bb = *(const float2*)(bpL + 2 * d);
                    #pragma unroll
                    for (int mt = 0; mt < 2; ++mt) {
                        f32x4 v = acc[mt][nt];
                        float pp[4];
                        #pragma unroll
                        for (int r = 0; r < 4; ++r) pp[r] = __shfl_xor(v[r], 1);
                        #pragma unroll
                        for (int rr = 0; rr < 2; ++rr) {
                            const int r = (odd ? 2 : 0) + rr;
                            float tpre = (odd ? pp[r] : v[r]) + bb.x;
                            float fpre = (odd ? v[r] : pp[r]) + bb.y;
                            tpre = fminf(30.f, fmaxf(-30.f, tpre));
                            fpre = fminf(15.f, fmaxf(-15.f, fpre));
                            float tau = 1.0f / (1.0f + __expf(-tpre)) + 1e-6f;
                            float e2  = __expf(2.0f * fpre);
                            float fo  = (e2 - 1.0f) / (e2 + 1.0f);
                            const int row = mt * 16 + quad * 4 + r;
                            const int seg = d >> 3;
                            const int idx = row * 256 +
                                (((seg & 24) | ((seg & 7) ^ (row & 7))) << 3) + (d & 7);
                            float h  = (float)Ahi[idx];
                            float nv = h + DT * (fo - h / tau);
                            nv = fminf(10.0f, fmaxf(-10.0f, nv));
                            Ahi[idx] = (bf16)nv;
                            dmax = fmaxf(dmax, fabsf(nv - h));
                        }
                    }
                }
            }
            __syncthreads();   // h updates visible before next layer's reads
        } // L

        #pragma unroll
        for (int off = 32; off > 0; off >>= 1)
            dmax = fmaxf(dmax, __shfl_xor(dmax, off));
        if (lane == 0)
            atomicMax((unsigned int*)(deltas + t), __float_as_uint(dmax));
    } // t

    // ---- final output: layer-3 states, de-swizzled, bf16 -> fp32 ----
    #pragma unroll
    for (int it = 0; it < 2; ++it) {
        int s = tid + it * 512;
        int r = s >> 5, seg = s & 31;
        int pseg = (seg & 24) | ((seg & 7) ^ (r & 7));
        bf16x8 v = *(const bf16x8*)&sH[NLAYER - 1][r * 256 + pseg * 8];
        float* go = out + (rowbase + r) * HID + seg * 8;
        float4 o0 = {(float)v[0], (float)v[1], (float)v[2], (float)v[3]};
        float4 o1 = {(float)v[4], (float)v[5], (float)v[6], (float)v[7]};
        *(float4*)go = o0;
        *(float4*)(go + 4) = o1;
    }
}

__global__ void result_kernel(const float* __restrict__ deltas,
                              float* __restrict__ out) {
    if (threadIdx.x == 0) {
        int res = TMAX;
        for (int t = 0; t < TMAX; ++t) {
            if (deltas[t] < EPSC) { res = t; break; }
        }
        out[(size_t)ROWS * HID] = (float)res;
    }
}

// ---------------------------------------------------------------------------
extern "C" void kernel_launch(void* const* d_in, const int* in_sizes, int n_in,
                              void* d_out, int out_size, void* d_ws, size_t ws_size,
                              hipStream_t stream) {
    const float* x  = (const float*)d_in[0];
    const float* Ws = (const float*)d_in[1];
    const float* bs = (const float*)d_in[2];
    const float* Wi = (const float*)d_in[3];
    const float* bi = (const float*)d_in[4];
    const float* Wt = (const float*)d_in[5];
    const float* bt = (const float*)d_in[6];
    float* out = (float*)d_out;

    char* p = (char*)d_ws;
    bf16*  WpT    = (bf16*)p;  p += (size_t)NLAYER * TWOH * TWOH * sizeof(bf16); // 2 MB
    float* bp     = (float*)p; p += (size_t)NLAYER * TWOH * sizeof(float);       // 8 KB
    float* deltas = (float*)p; p += 64 * sizeof(float);

    hipMemsetAsync(deltas, 0, 64 * sizeof(float), stream);
    pack_w_kernel<<<(NLAYER * TWOH * TWOH) / 256, 256, 0, stream>>>(Ws, Wi, Wt, WpT);
    pack_b_kernel<<<(NLAYER * TWOH) / 256, 256, 0, stream>>>(bs, bi, bt, bp);

    persistent_kernel<<<256, 512, 0, stream>>>(x, WpT, bp, deltas, out);
    result_kernel<<<1, 64, 0, stream>>>(deltas, out);
}

// Round 4
// 1764.557 us; speedup vs baseline: 9.3568x; 2.0598x over previous
//
#include <hip/hip_runtime.h>
#include <math.h>

#define HID 256
#define TWOH 512
#define ROWS 8192   // B*S
#define NLAYER 4
#define TMAX 50
#define DT 0.05f
#define EPSC 1e-3f

typedef __bf16 bf16;
typedef __bf16 bf16x8 __attribute__((ext_vector_type(8)));
typedef float f32x4 __attribute__((ext_vector_type(4)));

// ---------------------------------------------------------------------------
// Fragment-major weight packing. Logical B[n][k] per layer with interleaved
// columns: n=2d -> tau col d (Wt[d][k]); n=2d+1 -> forcing col d
// (k<256 ? Wi[d][k] : Ws[d][k-256]).
// Stored so that wave wv, k-chunk ci, n-tile nt reads ONE contiguous 1-KB
// fragment: elem index e = (((L*8+wv)*16+ci)*4+nt)*512 + lane*8 + j,
// where n = wv*64 + nt*16 + (lane&15), k = ci*32 + (lane>>4)*8 + j.
// ---------------------------------------------------------------------------
__global__ void pack_w_kernel(const float* __restrict__ Ws,
                              const float* __restrict__ Wi,
                              const float* __restrict__ Wt,
                              bf16* __restrict__ Wf) {
    int e = blockIdx.x * 256 + threadIdx.x;     // [0, 4*512*512)
    int j    = e & 7;
    int lane = (e >> 3) & 63;
    int nt   = (e >> 9) & 3;
    int ci   = (e >> 11) & 15;
    int wv   = (e >> 15) & 7;
    int L    = (e >> 18);
    int n = wv * 64 + nt * 16 + (lane & 15);
    int k = ci * 32 + (lane >> 4) * 8 + j;
    int d = n >> 1;
    float v;
    if ((n & 1) == 0) {
        v = Wt[(size_t)L * HID * TWOH + (size_t)d * TWOH + k];
    } else {
        v = (k < HID) ? Wi[(size_t)L * HID * HID + (size_t)d * HID + k]
                      : Ws[(size_t)L * HID * HID + (size_t)d * HID + (k - HID)];
    }
    Wf[e] = (bf16)v;
}

__global__ void pack_b_kernel(const float* __restrict__ bs,
                              const float* __restrict__ bi,
                              const float* __restrict__ bt,
                              float* __restrict__ bp) {
    int idx = blockIdx.x * 256 + threadIdx.x;   // [0, 4*512)
    int L = idx / TWOH;
    int n = idx % TWOH;
    int d = n >> 1;
    bp[idx] = ((n & 1) == 0) ? bt[L * HID + d]
                             : (bs[L * HID + d] + bi[L * HID + d]);
}

// ---------------------------------------------------------------------------
// Persistent kernel: block b owns rows [32b, 32b+32) for all 50 t x 4 layers.
// States LDS-resident bf16 (XOR-swizzled). Weights stream L2 -> registers as
// contiguous 1-KB fragments, depth-3 prefetch. 8 waves split n (64 each).
// ---------------------------------------------------------------------------
__global__ __launch_bounds__(512, 1) void persistent_kernel(
    const float* __restrict__ x,
    const bf16* __restrict__ Wf,
    const float* __restrict__ bp,
    float* __restrict__ deltas,
    float* __restrict__ out)
{
    __shared__ bf16 sX[32 * 256];            // 16 KB
    __shared__ bf16 sH[NLAYER][32 * 256];    // 64 KB
    __shared__ float sRed[8];

    const int tid  = threadIdx.x;
    const int lane = tid & 63;
    const int wv   = tid >> 6;               // 0..7
    const int l15  = lane & 15;
    const int quad = lane >> 4;              // 0..3
    const int w64  = wv * 64;
    const size_t rowbase = (size_t)blockIdx.x * 32;

    // ---- stage x -> sX (bf16, swizzled); zero sH ----
    #pragma unroll
    for (int it = 0; it < 2; ++it) {
        int s = tid + it * 512;              // 32 rows x 32 segs
        int r = s >> 5, seg = s & 31;
        const float* gx = x + (rowbase + r) * HID + seg * 8;
        float4 v0 = *(const float4*)gx;
        float4 v1 = *(const float4*)(gx + 4);
        bf16x8 o;
        o[0]=(bf16)v0.x; o[1]=(bf16)v0.y; o[2]=(bf16)v0.z; o[3]=(bf16)v0.w;
        o[4]=(bf16)v1.x; o[5]=(bf16)v1.y; o[6]=(bf16)v1.z; o[7]=(bf16)v1.w;
        int pseg = (seg & 24) | ((seg & 7) ^ (r & 7));
        *(bf16x8*)&sX[r * 256 + pseg * 8] = o;
    }
    {
        bf16x8 z = {};
        bf16* hflat = &sH[0][0];
        #pragma unroll
        for (int it = 0; it < 8; ++it)
            *(bf16x8*)&hflat[(size_t)(tid + it * 512) * 8] = z;
    }

    // ---- hoist biases: bias[L][nt] = (b_tau, b_forcing) for this lane's d ----
    float2 bias[NLAYER][4];
    #pragma unroll
    for (int L = 0; L < NLAYER; ++L)
        #pragma unroll
        for (int nt = 0; nt < 4; ++nt)
            bias[L][nt] = *(const float2*)(bp + L * TWOH + 2 * ((w64 + nt * 16 + l15) >> 1));

    __syncthreads();

    for (int t = 0; t < TMAX; ++t) {
        float dmax = 0.0f;
        for (int L = 0; L < NLAYER; ++L) {
            const bf16* Alo = (L == 0) ? sX : sH[L - 1];   // k < 256 (cur_in)
            bf16*       Ahi = sH[L];                       // k >= 256 (h_prev)
            // wave's fragment stream: 64 KB contiguous per (L, wv)
            const bf16* wb = Wf + ((size_t)(L * 8 + wv) * 32768) + (size_t)lane * 8;

            f32x4 acc[2][4];
            #pragma unroll
            for (int mt = 0; mt < 2; ++mt)
                #pragma unroll
                for (int nt = 0; nt < 4; ++nt)
                    acc[mt][nt] = (f32x4){0.f, 0.f, 0.f, 0.f};

            // depth-3 register prefetch of B fragments (1 KB each, contiguous)
            bf16x8 bb[3][4];
            #pragma unroll
            for (int pi = 0; pi < 3; ++pi)
                #pragma unroll
                for (int nt = 0; nt < 4; ++nt)
                    bb[pi][nt] = *(const bf16x8*)(wb + (size_t)(pi * 4 + nt) * 512);

            #pragma unroll
            for (int ci = 0; ci < 16; ++ci) {              // k = 32*ci
                const int p = ci % 3;
                const bf16* Asrc = (ci < 8) ? Alo : Ahi;   // static under unroll
                const int segb = (ci & 7) * 4 + quad;
                bf16x8 a[2];
                #pragma unroll
                for (int mt = 0; mt < 2; ++mt) {
                    int row  = mt * 16 + l15;
                    int pseg = (segb & 24) | ((segb & 7) ^ (row & 7));
                    a[mt] = *(const bf16x8*)&Asrc[row * 256 + pseg * 8];
                }
                #pragma unroll
                for (int mt = 0; mt < 2; ++mt)
                    #pragma unroll
                    for (int nt = 0; nt < 4; ++nt)
                        acc[mt][nt] = __builtin_amdgcn_mfma_f32_16x16x32_bf16(
                            a[mt], bb[p][nt], acc[mt][nt], 0, 0, 0);
                if (ci + 3 < 16) {
                    #pragma unroll
                    for (int nt = 0; nt < 4; ++nt)
                        bb[p][nt] = *(const bf16x8*)(wb + (size_t)((ci + 3) * 4 + nt) * 512);
                }
            }

            __syncthreads();   // all MFMA reads of sH[L] done before overwrite

            // Epilogue. C/D: col = l15 (+16nt +64wv), row = quad*4+reg.
            // Lane pair (l, l^1) shares d; even lane does regs 0,1, odd 2,3.
            {
                const int odd = lane & 1;
                #pragma unroll
                for (int nt = 0; nt < 4; ++nt) {
                    const int d = (w64 + nt * 16 + l15) >> 1;
                    const float2 bb2 = bias[L][nt];
                    #pragma unroll
                    for (int mt = 0; mt < 2; ++mt) {
                        f32x4 v = acc[mt][nt];
                        float pp[4];
                        #pragma unroll
                        for (int r = 0; r < 4; ++r) pp[r] = __shfl_xor(v[r], 1);
                        #pragma unroll
                        for (int rr = 0; rr < 2; ++rr) {
                            const int r = (odd ? 2 : 0) + rr;
                            float tpre = (odd ? pp[r] : v[r]) + bb2.x;
                            float fpre = (odd ? v[r] : pp[r]) + bb2.y;
                            tpre = fminf(30.f, fmaxf(-30.f, tpre));
                            fpre = fminf(15.f, fmaxf(-15.f, fpre));
                            // h/(sigma(tpre)+1e-6) == h*(1+u)/(1+eps*(1+u)), u=e^-t
                            float u   = __expf(-tpre);
                            float den = 1.0f + 1e-6f + 1e-6f * u;
                            float rcp = __builtin_amdgcn_rcpf(den);
                            float e2  = __expf(2.0f * fpre);
                            float d2  = e2 + 1.0f;
                            float r2  = __builtin_amdgcn_rcpf(d2);
                            float fo  = (e2 - 1.0f) * r2;
                            const int row = mt * 16 + quad * 4 + r;
                            const int seg = d >> 3;
                            const int idx = row * 256 +
                                (((seg & 24) | ((seg & 7) ^ (row & 7))) << 3) + (d & 7);
                            float h  = (float)Ahi[idx];
                            float g  = h * (1.0f + u) * rcp;
                            float nv = h + DT * (fo - g);
                            nv = fminf(10.0f, fmaxf(-10.0f, nv));
                            Ahi[idx] = (bf16)nv;
                            dmax = fmaxf(dmax, fabsf(nv - h));
                        }
                    }
                }
            }
            if (L == NLAYER - 1) {
                #pragma unroll
                for (int off = 32; off > 0; off >>= 1)
                    dmax = fmaxf(dmax, __shfl_xor(dmax, off));
                if (lane == 0) sRed[wv] = dmax;
            }
            __syncthreads();   // h updates (and sRed) visible
        } // L

        if (tid == 0) {
            float m = sRed[0];
            #pragma unroll
            for (int w = 1; w < 8; ++w) m = fmaxf(m, sRed[w]);
            atomicMax((unsigned int*)(deltas + t), __float_as_uint(m));
        }
    } // t

    // ---- final output: layer-3 states, de-swizzled, bf16 -> fp32 ----
    #pragma unroll
    for (int it = 0; it < 2; ++it) {
        int s = tid + it * 512;
        int r = s >> 5, seg = s & 31;
        int pseg = (seg & 24) | ((seg & 7) ^ (r & 7));
        bf16x8 v = *(const bf16x8*)&sH[NLAYER - 1][r * 256 + pseg * 8];
        float* go = out + (rowbase + r) * HID + seg * 8;
        float4 o0 = {(float)v[0], (float)v[1], (float)v[2], (float)v[3]};
        float4 o1 = {(float)v[4], (float)v[5], (float)v[6], (float)v[7]};
        *(float4*)go = o0;
        *(float4*)(go + 4) = o1;
    }
}

__global__ void result_kernel(const float* __restrict__ deltas,
                              float* __restrict__ out) {
    if (threadIdx.x == 0) {
        int res = TMAX;
        for (int t = 0; t < TMAX; ++t) {
            if (deltas[t] < EPSC) { res = t; break; }
        }
        out[(size_t)ROWS * HID] = (float)res;
    }
}

// ---------------------------------------------------------------------------
extern "C" void kernel_launch(void* const* d_in, const int* in_sizes, int n_in,
                              void* d_out, int out_size, void* d_ws, size_t ws_size,
                              hipStream_t stream) {
    const float* x  = (const float*)d_in[0];
    const float* Ws = (const float*)d_in[1];
    const float* bs = (const float*)d_in[2];
    const float* Wi = (const float*)d_in[3];
    const float* bi = (const float*)d_in[4];
    const float* Wt = (const float*)d_in[5];
    const float* bt = (const float*)d_in[6];
    float* out = (float*)d_out;

    char* p = (char*)d_ws;
    bf16*  Wf     = (bf16*)p;  p += (size_t)NLAYER * TWOH * TWOH * sizeof(bf16); // 2 MB
    float* bp     = (float*)p; p += (size_t)NLAYER * TWOH * sizeof(float);       // 8 KB
    float* deltas = (float*)p; p += 64 * sizeof(float);

    hipMemsetAsync(deltas, 0, 64 * sizeof(float), stream);
    pack_w_kernel<<<(NLAYER * TWOH * TWOH) / 256, 256, 0, stream>>>(Ws, Wi, Wt, Wf);
    pack_b_kernel<<<(NLAYER * TWOH) / 256, 256, 0, stream>>>(bs, bi, bt, bp);

    persistent_kernel<<<256, 512, 0, stream>>>(x, Wf, bp, deltas, out);
    result_kernel<<<1, 64, 0, stream>>>(deltas, out);
}